// Round 1
// baseline (141.091 us; speedup 1.0000x reference)
//
#include <hip/hip_runtime.h>

#define W 256
#define NA 180

__global__ __launch_bounds__(256) void radon_kernel(
    const float* __restrict__ x, const int* __restrict__ index_p,
    float* __restrict__ out)
{
    const int a = blockIdx.x;   // angle 0..179
    const int n = blockIdx.y;   // batch
    const int c = threadIdx.x;  // column 0..255

    const int index = *index_p;
    const int seg[6] = {1, 26, 51, 77, 102, 128};
    const int t0 = seg[4 - index];
    const int t1 = seg[4 - index + 1];

    const float th = (float)a * 0.017453292519943295f; // deg2rad
    float sa, ca;
    sincosf(th, &sa, &ca);

    const float xc = ((2.0f * (float)c + 1.0f) * (1.0f / (float)W)) - 1.0f;

    // ix(r) = 128*ca*xc + sa*(r-127.5) + 127.5
    // iy(r) = -128*sa*xc + ca*(r-127.5) + 127.5
    const float bx = 128.0f * ca * xc + 127.5f;
    const float by = -128.0f * sa * xc + 127.5f;

    const float* __restrict__ img = x + (size_t)n * W * W;

    const int r1lo = 128 - t1, r1hi = 127 + t1;
    const int r0lo = 128 - t0, r0hi = 127 + t0;

    float sum0 = 0.0f, sum1 = 0.0f;

    for (int r = r1lo; r <= r1hi; ++r) {
        const float rf = (float)r - 127.5f;
        const float ix = fmaf(sa, rf, bx);
        const float iy = fmaf(ca, rf, by);
        const float ix0f = floorf(ix);
        const float iy0f = floorf(iy);
        const float wx1 = ix - ix0f;
        const float wy1 = iy - iy0f;
        const int ix0 = (int)ix0f;
        const int iy0 = (int)iy0f;

        const int x0c = min(max(ix0, 0), W - 1);
        const int x1c = min(max(ix0 + 1, 0), W - 1);
        const int y0c = min(max(iy0, 0), W - 1);
        const int y1c = min(max(iy0 + 1, 0), W - 1);
        const bool vx0 = (ix0 >= 0) && (ix0 < W);
        const bool vx1 = (ix0 + 1 >= 0) && (ix0 + 1 < W);
        const bool vy0 = (iy0 >= 0) && (iy0 < W);
        const bool vy1 = (iy0 + 1 >= 0) && (iy0 + 1 < W);

        float v00 = img[y0c * W + x0c];
        float v01 = img[y0c * W + x1c];
        float v10 = img[y1c * W + x0c];
        float v11 = img[y1c * W + x1c];
        if (!(vy0 && vx0)) v00 = 0.0f;
        if (!(vy0 && vx1)) v01 = 0.0f;
        if (!(vy1 && vx0)) v10 = 0.0f;
        if (!(vy1 && vx1)) v11 = 0.0f;

        // bilinear: (1-wy)*((1-wx)*v00 + wx*v01) + wy*((1-wx)*v10 + wx*v11)
        const float top = fmaf(wx1, v01 - v00, v00);
        const float bot = fmaf(wx1, v11 - v10, v10);
        const float val = fmaf(wy1, bot - top, top);

        sum1 += val;
        if (r >= r0lo && r <= r0hi) sum0 += val;
    }

    // out shape (N, 2, W, NA): out[n][s][c][a]
    out[(((size_t)n * 2 + 0) * W + c) * NA + a] = sum0 * (1.0f / (float)(2 * t0));
    out[(((size_t)n * 2 + 1) * W + c) * NA + a] = sum1 * (1.0f / (float)(2 * t1));
}

extern "C" void kernel_launch(void* const* d_in, const int* in_sizes, int n_in,
                              void* d_out, int out_size, void* d_ws, size_t ws_size,
                              hipStream_t stream) {
    const float* x = (const float*)d_in[0];
    const int* index_p = (const int*)d_in[1];
    float* out = (float*)d_out;
    const int N = in_sizes[0] / (W * W); // 4
    dim3 grid(NA, N);
    radon_kernel<<<grid, 256, 0, stream>>>(x, index_p, out);
}